// Round 1
// baseline (656.505 us; speedup 1.0000x reference)
//
#include <hip/hip_runtime.h>
#include <math.h>

#define NB 2
#define NCH 48
#define P 13824        // 24^3
#define DI 96
#define NSTATE 16
#define L 13824
#define CHUNK 128
#define NCK 108        // L / CHUNK

__device__ __forceinline__ float siluf(float x) { return x / (1.f + __expf(-x)); }
__device__ __forceinline__ float softplusf(float x) {
    return x > 0.f ? x + log1pf(expf(-x)) : log1pf(expf(x));
}

// ---------------- K1: upsample(2x trilinear, align_corners) + concat + 1x1x1 conv ----------------
__global__ __launch_bounds__(256) void k_conv1(const float* __restrict__ x,
    const float* __restrict__ Hx, const float* __restrict__ W1,
    const float* __restrict__ b1, float* __restrict__ h1)
{
    __shared__ float w[48 * 144];
    for (int i = threadIdx.x; i < 48 * 144; i += 256) w[i] = W1[i];
    __syncthreads();
    int t = blockIdx.x * 256 + threadIdx.x;   // 0 .. NB*P-1
    int b = t / P, p = t % P;
    int zi = p / 576, yi = (p / 24) % 24, xi_ = p % 24;
    float fpos; int z0, z1, y0, y1, x0, x1; float wz, wy, wx;
    fpos = (float)(zi * 11) / 23.0f; z0 = (int)floorf(fpos); wz = fpos - z0; z1 = min(z0 + 1, 11);
    fpos = (float)(yi * 11) / 23.0f; y0 = (int)floorf(fpos); wy = fpos - y0; y1 = min(y0 + 1, 11);
    fpos = (float)(xi_ * 11) / 23.0f; x0 = (int)floorf(fpos); wx = fpos - x0; x1 = min(x0 + 1, 11);
    float acc[48];
#pragma unroll
    for (int o = 0; o < 48; ++o) acc[o] = b1[o];
    const float* xb = x + (size_t)b * 48 * 1728;
    for (int c = 0; c < 48; ++c) {
        const float* xc = xb + c * 1728;
        float v00 = xc[(z0*12+y0)*12+x0]*(1.f-wx) + xc[(z0*12+y0)*12+x1]*wx;
        float v01 = xc[(z0*12+y1)*12+x0]*(1.f-wx) + xc[(z0*12+y1)*12+x1]*wx;
        float v10 = xc[(z1*12+y0)*12+x0]*(1.f-wx) + xc[(z1*12+y0)*12+x1]*wx;
        float v11 = xc[(z1*12+y1)*12+x0]*(1.f-wx) + xc[(z1*12+y1)*12+x1]*wx;
        float v = (v00*(1.f-wy)+v01*wy)*(1.f-wz) + (v10*(1.f-wy)+v11*wy)*wz;
#pragma unroll
        for (int o = 0; o < 48; ++o) acc[o] = fmaf(w[o*144+c], v, acc[o]);
    }
    const float* hb = Hx + (size_t)b * 96 * P + p;
    for (int c = 0; c < 96; ++c) {
        float v = hb[(size_t)c * P];
#pragma unroll
        for (int o = 0; o < 48; ++o) acc[o] = fmaf(w[o*144+48+c], v, acc[o]);
    }
    float* out = h1 + (size_t)b * 48 * P + p;
#pragma unroll
    for (int o = 0; o < 48; ++o) out[(size_t)o * P] = acc[o];
}

// ---------------- K2: 3x3x3 conv, pad 1, 48->48, LDS-tiled 4^3 ----------------
__global__ __launch_bounds__(256) void k_conv2(const float* __restrict__ h1,
    const float* __restrict__ W2, const float* __restrict__ b2, float* __restrict__ h2)
{
    __shared__ float tile[48 * 216];   // 48 x 6x6x6
    int blk = blockIdx.x;              // b*216 + tz*36 + ty*6 + tx
    int b = blk / 216; int r = blk % 216;
    int tz = r / 36, ty = (r / 6) % 6, tx = r % 6;
    int z0 = tz*4 - 1, y0 = ty*4 - 1, x0 = tx*4 - 1;
    for (int i = threadIdx.x; i < 48 * 216; i += 256) {
        int c = i / 216; int q = i % 216;
        int lz = q / 36, ly = (q / 6) % 6, lx = q % 6;
        int gz = z0 + lz, gy = y0 + ly, gx = x0 + lx;
        float v = 0.f;
        if ((unsigned)gz < 24u && (unsigned)gy < 24u && (unsigned)gx < 24u)
            v = h1[((size_t)(b*48 + c)) * P + (gz*24 + gy)*24 + gx];
        tile[i] = v;
    }
    __syncthreads();
    int lp = threadIdx.x & 63;
    int og = threadIdx.x >> 6;   // 0..3, uniform per wave
    int lz = lp >> 4, ly = (lp >> 2) & 3, lx = lp & 3;
    float acc[12];
#pragma unroll
    for (int i = 0; i < 12; ++i) acc[i] = b2[og*12 + i];
    const float* wbase = W2 + (size_t)og * 12 * 48 * 27;
    for (int c = 0; c < 48; ++c) {
        const float* tc = tile + c * 216;
#pragma unroll
        for (int dz = 0; dz < 3; ++dz)
#pragma unroll
        for (int dy = 0; dy < 3; ++dy)
#pragma unroll
        for (int dx = 0; dx < 3; ++dx) {
            float v = tc[(lz+dz)*36 + (ly+dy)*6 + (lx+dx)];
            int tap = c*27 + (dz*3 + dy)*3 + dx;
#pragma unroll
            for (int i = 0; i < 12; ++i)
                acc[i] = fmaf(wbase[i*48*27 + tap], v, acc[i]);
        }
    }
    int gz = tz*4 + lz, gy = ty*4 + ly, gx = tx*4 + lx;
    size_t pp = (size_t)(gz*24 + gy)*24 + gx;
#pragma unroll
    for (int i = 0; i < 12; ++i)
        h2[((size_t)(b*48) + og*12 + i) * P + pp] = acc[i];
}

// ---------------- K3: 1x1x1 conv 48->48 ----------------
__global__ __launch_bounds__(256) void k_conv3(const float* __restrict__ h2,
    const float* __restrict__ W3, const float* __restrict__ b3, float* __restrict__ h3)
{
    __shared__ float w[48 * 48];
    for (int i = threadIdx.x; i < 2304; i += 256) w[i] = W3[i];
    __syncthreads();
    int t = blockIdx.x * 256 + threadIdx.x;
    int b = t / P, p = t % P;
    float acc[48];
#pragma unroll
    for (int o = 0; o < 48; ++o) acc[o] = b3[o];
    const float* hb = h2 + (size_t)b * 48 * P + p;
    for (int c = 0; c < 48; ++c) {
        float v = hb[(size_t)c * P];
#pragma unroll
        for (int o = 0; o < 48; ++o) acc[o] = fmaf(w[o*48+c], v, acc[o]);
    }
    float* out = h3 + (size_t)b * 48 * P + p;
#pragma unroll
    for (int o = 0; o < 48; ++o) out[(size_t)o * P] = acc[o];
}

// ---------------- K4: instance-norm stats ----------------
__global__ __launch_bounds__(256) void k_in_stats(const float* __restrict__ h3,
                                                  float* __restrict__ stats)
{
    int bc = blockIdx.x;   // 0..95
    const float* src = h3 + (size_t)bc * P;
    float s = 0.f, s2 = 0.f;
    for (int i = threadIdx.x; i < P; i += 256) { float v = src[i]; s += v; s2 += v*v; }
    __shared__ float rs[4], rs2[4];
    for (int off = 32; off; off >>= 1) { s += __shfl_down(s, off); s2 += __shfl_down(s2, off); }
    int wid = threadIdx.x >> 6;
    if ((threadIdx.x & 63) == 0) { rs[wid] = s; rs2[wid] = s2; }
    __syncthreads();
    if (threadIdx.x == 0) {
        s = rs[0] + rs[1] + rs[2] + rs[3];
        s2 = rs2[0] + rs2[1] + rs2[2] + rs2[3];
        float m = s / (float)P;
        float var = s2 / (float)P - m * m;
        stats[bc*2] = m;
        stats[bc*2 + 1] = rsqrtf(var + 1e-5f);
    }
}

// ---------------- K5: normalize + SELU (in place) ----------------
__global__ __launch_bounds__(256) void k_in_apply(float* __restrict__ h3,
                                                  const float* __restrict__ stats)
{
    int t = blockIdx.x * 256 + threadIdx.x;  // NB*48*P exact
    int bc = t / P;
    float m = stats[bc*2], istd = stats[bc*2 + 1];
    float v = (h3[t] - m) * istd;
    const float kScale = 1.0507009873554805f, kAlpha = 1.6732632423543772f;
    h3[t] = v > 0.f ? kScale * v : kScale * kAlpha * expm1f(v);
}

// ---------------- K6: in_proj (u @ W^T -> xi, z) ----------------
__global__ __launch_bounds__(192) void k_inproj(const float* __restrict__ Lx,
    const float* __restrict__ Wip, float* __restrict__ xi, float* __restrict__ z)
{
    __shared__ float u[48 * 64];
    int b = blockIdx.x / 216; int l0 = (blockIdx.x % 216) * 64;
    for (int i = threadIdx.x; i < 48 * 64; i += 192) {
        int c = i >> 6, ll = i & 63;
        u[i] = Lx[((size_t)(b*48) + c) * P + l0 + ll];
    }
    __syncthreads();
    int e = threadIdx.x;   // 0..191
    float w[48];
#pragma unroll
    for (int c = 0; c < 48; ++c) w[c] = Wip[e*48 + c];
    float* dst = (e < 96) ? (xi + ((size_t)b * L + l0) * 96 + e)
                          : (z  + ((size_t)b * L + l0) * 96 + (e - 96));
    for (int ll = 0; ll < 64; ++ll) {
        float acc = 0.f;
#pragma unroll
        for (int c = 0; c < 48; ++c) acc = fmaf(w[c], u[c*64 + ll], acc);
        dst[(size_t)ll * 96] = acc;
    }
}

// ---------------- K7: depthwise causal conv1d + silu ----------------
__global__ __launch_bounds__(256) void k_conv1d(const float* __restrict__ xi,
    const float* __restrict__ cw, const float* __restrict__ cb, float* __restrict__ xs)
{
    int t = blockIdx.x * 256 + threadIdx.x;   // NB*L*96 exact
    int d = t % 96; int bl = t / 96; int l = bl % L; int b = bl / L;
    float acc = cb[d];
    const float* src = xi + ((size_t)b * L) * 96 + d;
#pragma unroll
    for (int k = 0; k < 4; ++k) {
        int ls = l - 3 + k;
        if (ls >= 0) acc = fmaf(cw[d*4 + k], src[(size_t)ls * 96], acc);
    }
    xs[t] = siluf(acc);
}

// ---------------- K8: x_proj + dt_proj + softplus ----------------
__global__ __launch_bounds__(256) void k_xproj(const float* __restrict__ xs,
    const float* __restrict__ Wxp, const float* __restrict__ Wdt,
    const float* __restrict__ bdt, float* __restrict__ delta,
    float* __restrict__ Bm, float* __restrict__ Cm)
{
    __shared__ float wx[35 * 96];
    __shared__ float wd[96 * 3];
    __shared__ float bd[96];
    for (int i = threadIdx.x; i < 35 * 96; i += 256) wx[i] = Wxp[i];
    for (int i = threadIdx.x; i < 96 * 3; i += 256) wd[i] = Wdt[i];
    if (threadIdx.x < 96) bd[threadIdx.x] = bdt[threadIdx.x];
    __syncthreads();
    int t = blockIdx.x * 256 + threadIdx.x;   // NB*L exact
    const float* row = xs + (size_t)t * 96;
    float xr[96];
#pragma unroll
    for (int i = 0; i < 24; ++i) {
        float4 v = ((const float4*)row)[i];
        xr[i*4] = v.x; xr[i*4+1] = v.y; xr[i*4+2] = v.z; xr[i*4+3] = v.w;
    }
    float dt0 = 0.f, dt1 = 0.f, dt2 = 0.f;
#pragma unroll
    for (int d = 0; d < 96; ++d) {
        dt0 = fmaf(wx[0*96 + d], xr[d], dt0);
        dt1 = fmaf(wx[1*96 + d], xr[d], dt1);
        dt2 = fmaf(wx[2*96 + d], xr[d], dt2);
    }
#pragma unroll
    for (int e = 0; e < 16; ++e) {
        float a = 0.f, c = 0.f;
#pragma unroll
        for (int d = 0; d < 96; ++d) {
            a = fmaf(wx[(3 + e)*96 + d], xr[d], a);
            c = fmaf(wx[(19 + e)*96 + d], xr[d], c);
        }
        Bm[(size_t)t * 16 + e] = a;
        Cm[(size_t)t * 16 + e] = c;
    }
    float* dl = delta + (size_t)t * 96;
#pragma unroll
    for (int d = 0; d < 96; ++d) {
        float v = fmaf(wd[d*3], dt0, fmaf(wd[d*3+1], dt1, fmaf(wd[d*3+2], dt2, bd[d])));
        dl[d] = softplusf(v);
    }
}

// ---------------- K9: scan phase 1 (per-chunk local scan + dA product) ----------------
__global__ __launch_bounds__(256) void k_scan1(const float* __restrict__ delta,
    const float* __restrict__ xs, const float* __restrict__ Bm,
    const float* __restrict__ Alog, float* __restrict__ Aprod, float* __restrict__ hend)
{
    int wid = (blockIdx.x * 256 + threadIdx.x) >> 6;  // 0 .. NB*NCK*24-1
    int lane = threadIdx.x & 63;
    int dg = wid % 24; int ch = (wid / 24) % NCK; int b = wid / (24 * NCK);
    int dl = lane >> 4, n = lane & 15;
    int d = dg * 4 + dl;
    float A = -__expf(Alog[d*16 + n]);
    float h = 0.f, ap = 1.f;
    int t0 = ch * CHUNK;
    const float* dp = delta + ((size_t)b * L + t0) * 96 + d;
    const float* xp = xs    + ((size_t)b * L + t0) * 96 + d;
    const float* bp = Bm    + ((size_t)b * L + t0) * 16 + n;
    for (int t = 0; t < CHUNK; ++t) {
        float del = dp[(size_t)t * 96];
        float xv  = xp[(size_t)t * 96];
        float bv  = bp[(size_t)t * 16];
        float dA = __expf(del * A);
        h = fmaf(dA, h, del * xv * bv);
        ap *= dA;
    }
    size_t idx = (((size_t)b * NCK + ch) * 96 + d) * 16 + n;
    Aprod[idx] = ap;
    hend[idx]  = h;
}

// ---------------- K10: scan phase 2 (cross-chunk combine) ----------------
__global__ __launch_bounds__(256) void k_scan2(const float* __restrict__ Aprod,
    const float* __restrict__ hend, float* __restrict__ hin)
{
    int t = blockIdx.x * 256 + threadIdx.x;   // NB*1536 exact
    int b = t / 1536; int dn = t % 1536;
    float carry = 0.f;
    for (int j = 0; j < NCK; ++j) {
        size_t idx = ((size_t)b * NCK + j) * 1536 + dn;
        hin[idx] = carry;
        carry = fmaf(Aprod[idx], carry, hend[idx]);
    }
}

// ---------------- K11: scan phase 3 (replay + y = (scan + D*xs)*silu(z), in place over xs) ----------------
__global__ __launch_bounds__(256) void k_scan3(const float* __restrict__ delta,
    float* __restrict__ xs, const float* __restrict__ Bm, const float* __restrict__ Cm,
    const float* __restrict__ z, const float* __restrict__ Alog,
    const float* __restrict__ Dp, const float* __restrict__ hin)
{
    int wid = (blockIdx.x * 256 + threadIdx.x) >> 6;
    int lane = threadIdx.x & 63;
    int dg = wid % 24; int ch = (wid / 24) % NCK; int b = wid / (24 * NCK);
    int dl = lane >> 4, n = lane & 15;
    int d = dg * 4 + dl;
    float A = -__expf(Alog[d*16 + n]);
    float Dv = Dp[d];
    size_t cidx = (((size_t)b * NCK + ch) * 96 + d) * 16 + n;
    float h = hin[cidx];
    int t0 = ch * CHUNK;
    const float* dp = delta + ((size_t)b * L + t0) * 96 + d;
    float* xp       = xs    + ((size_t)b * L + t0) * 96 + d;
    const float* bp = Bm    + ((size_t)b * L + t0) * 16 + n;
    const float* cp = Cm    + ((size_t)b * L + t0) * 16 + n;
    const float* zp = z     + ((size_t)b * L + t0) * 96 + d;
    for (int t = 0; t < CHUNK; ++t) {
        float del = dp[(size_t)t * 96];
        float xv  = xp[(size_t)t * 96];
        float dA = __expf(del * A);
        h = fmaf(dA, h, del * xv * bp[(size_t)t * 16]);
        float yc = h * cp[(size_t)t * 16];
        yc += __shfl_xor(yc, 8);
        yc += __shfl_xor(yc, 4);
        yc += __shfl_xor(yc, 2);
        yc += __shfl_xor(yc, 1);
        if (n == 0) {
            float zv = zp[(size_t)t * 96];
            xp[(size_t)t * 96] = fmaf(Dv, xv, yc) * siluf(zv);
        }
    }
}

// ---------------- K12: out_proj + residual ----------------
__global__ __launch_bounds__(256) void k_outproj(const float* __restrict__ y,
    const float* __restrict__ Wop, const float* __restrict__ Lx, float* __restrict__ out)
{
    __shared__ float w[48 * 96];
    for (int i = threadIdx.x; i < 48 * 96; i += 256) w[i] = Wop[i];
    __syncthreads();
    int t = blockIdx.x * 256 + threadIdx.x;  // NB*P exact
    int b = t / P, p = t % P;
    const float* yr = y + (size_t)t * 96;
    float acc[48];
#pragma unroll
    for (int o = 0; o < 48; ++o) acc[o] = 0.f;
#pragma unroll
    for (int i = 0; i < 24; ++i) {
        float4 v4 = ((const float4*)yr)[i];
#pragma unroll
        for (int o = 0; o < 48; ++o) {
            acc[o] = fmaf(w[o*96 + i*4],     v4.x, acc[o]);
            acc[o] = fmaf(w[o*96 + i*4 + 1], v4.y, acc[o]);
            acc[o] = fmaf(w[o*96 + i*4 + 2], v4.z, acc[o]);
            acc[o] = fmaf(w[o*96 + i*4 + 3], v4.w, acc[o]);
        }
    }
    const float* lx = Lx + (size_t)b * 48 * P + p;
    float* op = out + (size_t)b * 48 * P + p;
#pragma unroll
    for (int o = 0; o < 48; ++o) op[(size_t)o * P] = acc[o] + lx[(size_t)o * P];
}

extern "C" void kernel_launch(void* const* d_in, const int* in_sizes, int n_in,
                              void* d_out, int out_size, void* d_ws, size_t ws_size,
                              hipStream_t stream) {
    const float* x        = (const float*)d_in[0];
    const float* Hx       = (const float*)d_in[1];
    const float* W1       = (const float*)d_in[2];
    const float* b1       = (const float*)d_in[3];
    const float* W2       = (const float*)d_in[4];
    const float* b2       = (const float*)d_in[5];
    const float* W3       = (const float*)d_in[6];
    const float* b3       = (const float*)d_in[7];
    const float* in_proj  = (const float*)d_in[8];
    const float* conv1d_w = (const float*)d_in[9];
    const float* conv1d_b = (const float*)d_in[10];
    const float* x_proj   = (const float*)d_in[11];
    const float* dt_proj  = (const float*)d_in[12];
    const float* dt_bias  = (const float*)d_in[13];
    const float* A_log    = (const float*)d_in[14];
    const float* D_param  = (const float*)d_in[15];
    const float* out_proj = (const float*)d_in[16];
    float* out = (float*)d_out;

    float* ws = (float*)d_ws;
    const size_t SZ_BCP = (size_t)NB * 48 * P;      // 1,327,104
    const size_t SZ_BLD = (size_t)NB * L * 96;      // 2,654,208
    const size_t SZ_BLN = (size_t)NB * L * 16;      //   442,368
    const size_t SZ_CK  = (size_t)NB * NCK * 1536;  //   331,776
    float* bufA  = ws;                    // h1; later delta (spans bufA+bufB)
    float* bufB  = bufA + SZ_BCP;         // h2
    float* bufC  = bufB + SZ_BCP;         // h3 -> Lx (in place)
    float* xib   = bufC + SZ_BCP;         // xi
    float* zb    = xib  + SZ_BLD;         // z
    float* xsb   = zb   + SZ_BLD;         // xs, then y (in place)
    float* Bmb   = xsb  + SZ_BLD;
    float* Cmb   = Bmb  + SZ_BLN;
    float* Apr   = Cmb  + SZ_BLN;
    float* hendb = Apr  + SZ_CK;
    float* hinb  = hendb+ SZ_CK;
    float* stats = hinb + SZ_CK;          // 192 floats
    float* deltab = bufA;                 // reuses h1+h2 (free after k_conv3)

    k_conv1<<<108, 256, 0, stream>>>(x, Hx, W1, b1, bufA);
    k_conv2<<<NB * 216, 256, 0, stream>>>(bufA, W2, b2, bufB);
    k_conv3<<<108, 256, 0, stream>>>(bufB, W3, b3, bufC);
    k_in_stats<<<NB * 48, 256, 0, stream>>>(bufC, stats);
    k_in_apply<<<5184, 256, 0, stream>>>(bufC, stats);
    k_inproj<<<NB * 216, 192, 0, stream>>>(bufC, in_proj, xib, zb);
    k_conv1d<<<10368, 256, 0, stream>>>(xib, conv1d_w, conv1d_b, xsb);
    k_xproj<<<108, 256, 0, stream>>>(xsb, x_proj, dt_proj, dt_bias, deltab, Bmb, Cmb);
    k_scan1<<<(NB * NCK * 24) / 4, 256, 0, stream>>>(deltab, xsb, Bmb, A_log, Apr, hendb);
    k_scan2<<<12, 256, 0, stream>>>(Apr, hendb, hinb);
    k_scan3<<<(NB * NCK * 24) / 4, 256, 0, stream>>>(deltab, xsb, Bmb, Cmb, zb, A_log,
                                                     D_param, hinb);
    k_outproj<<<108, 256, 0, stream>>>(xsb, out_proj, bufC, out);
}

// Round 2
// 495.471 us; speedup vs baseline: 1.3250x; 1.3250x over previous
//
#include <hip/hip_runtime.h>
#include <math.h>

#define NB 2
#define NCH 48
#define P 13824        // 24^3
#define DI 96
#define NSTATE 16
#define L 13824
#define CHUNK 128
#define NCK 108        // L / CHUNK

__device__ __forceinline__ float siluf(float x) { return x / (1.f + __expf(-x)); }
__device__ __forceinline__ float softplusf(float x) {
    return x > 0.f ? x + log1pf(expf(-x)) : log1pf(expf(x));
}

// ---------------- K0: transpose W2 [48o][48c][27t] -> Wt [4og][48c][27t][12i] ----------------
__global__ __launch_bounds__(256) void k_wtrans(const float* __restrict__ W2,
                                                float* __restrict__ Wt)
{
    int i = blockIdx.x * 256 + threadIdx.x;      // 62208 = 243*256 exact
    int o = i / (48 * 27); int r = i % (48 * 27); int c = r / 27; int tap = r % 27;
    int og = o / 12, oi = o % 12;
    Wt[(((og * 48 + c) * 27 + tap) * 12) + oi] = W2[i];
}

// ---------------- K1: upsample(2x trilinear) + concat + 1x1x1 conv (scalar weights) ----------------
__global__ __launch_bounds__(256) void k_conv1(const float* __restrict__ x,
    const float* __restrict__ Hx, const float* __restrict__ W1,
    const float* __restrict__ b1, float* __restrict__ h1)
{
    int t = blockIdx.x * 256 + threadIdx.x;   // 0 .. NB*P-1
    int b = t / P, p = t % P;
    int zi = p / 576, yi = (p / 24) % 24, xi_ = p % 24;
    float fpos; int z0, z1, y0, y1, x0, x1; float wz, wy, wx;
    fpos = (float)(zi * 11) / 23.0f; z0 = (int)floorf(fpos); wz = fpos - z0; z1 = min(z0 + 1, 11);
    fpos = (float)(yi * 11) / 23.0f; y0 = (int)floorf(fpos); wy = fpos - y0; y1 = min(y0 + 1, 11);
    fpos = (float)(xi_ * 11) / 23.0f; x0 = (int)floorf(fpos); wx = fpos - x0; x1 = min(x0 + 1, 11);
    float acc[48];
#pragma unroll
    for (int o = 0; o < 48; ++o) acc[o] = b1[o];          // uniform -> s_load
    const float* xb = x + (size_t)b * 48 * 1728;
    for (int c = 0; c < 48; ++c) {
        const float* xc = xb + c * 1728;
        float v00 = xc[(z0*12+y0)*12+x0]*(1.f-wx) + xc[(z0*12+y0)*12+x1]*wx;
        float v01 = xc[(z0*12+y1)*12+x0]*(1.f-wx) + xc[(z0*12+y1)*12+x1]*wx;
        float v10 = xc[(z1*12+y0)*12+x0]*(1.f-wx) + xc[(z1*12+y0)*12+x1]*wx;
        float v11 = xc[(z1*12+y1)*12+x0]*(1.f-wx) + xc[(z1*12+y1)*12+x1]*wx;
        float v = (v00*(1.f-wy)+v01*wy)*(1.f-wz) + (v10*(1.f-wy)+v11*wy)*wz;
#pragma unroll
        for (int o = 0; o < 48; ++o) acc[o] = fmaf(W1[o*144+c], v, acc[o]);   // uniform -> s_load
    }
    const float* hb = Hx + (size_t)b * 96 * P + p;
    for (int c = 0; c < 96; ++c) {
        float v = hb[(size_t)c * P];
#pragma unroll
        for (int o = 0; o < 48; ++o) acc[o] = fmaf(W1[o*144+48+c], v, acc[o]); // uniform -> s_load
    }
    float* out = h1 + (size_t)b * 48 * P + p;
#pragma unroll
    for (int o = 0; o < 48; ++o) out[(size_t)o * P] = acc[o];
}

// ---------------- K2: 3x3x3 conv, pad 1, 48->48, LDS tile + SGPR weights ----------------
__global__ __launch_bounds__(256) void k_conv2(const float* __restrict__ h1,
    const float* __restrict__ Wt, const float* __restrict__ b2, float* __restrict__ h2)
{
    __shared__ float tile[48 * 252];   // 48 x 6z x 6y x 7x (x padded 6->7)
    int blk = blockIdx.x;              // b*216 + tz*36 + ty*6 + tx
    int b = blk / 216; int r = blk % 216;
    int tz = r / 36, ty = (r / 6) % 6, tx = r % 6;
    int z0 = tz*4 - 1, y0 = ty*4 - 1, x0 = tx*4 - 1;
    for (int i = threadIdx.x; i < 48 * 216; i += 256) {
        int c = i / 216; int q = i % 216;
        int lz = q / 36, ly = (q / 6) % 6, lx = q % 6;
        int gz = z0 + lz, gy = y0 + ly, gx = x0 + lx;
        float v = 0.f;
        if ((unsigned)gz < 24u && (unsigned)gy < 24u && (unsigned)gx < 24u)
            v = h1[((size_t)(b*48 + c)) * P + (gz*24 + gy)*24 + gx];
        tile[c*252 + (lz*6 + ly)*7 + lx] = v;
    }
    __syncthreads();
    int lp = threadIdx.x & 63;
    int og = __builtin_amdgcn_readfirstlane((int)(threadIdx.x >> 6));  // SGPR -> scalar weight path
    int lz = lp >> 4, ly = (lp >> 2) & 3, lx = lp & 3;
    float acc[12];
#pragma unroll
    for (int i = 0; i < 12; ++i) acc[i] = b2[og*12 + i];   // uniform -> s_load
    const float* wb = Wt + (size_t)og * 48 * 27 * 12;
    for (int c = 0; c < 48; ++c) {
        const float* tc = tile + c * 252;
        const float* wc = wb + c * 27 * 12;
#pragma unroll
        for (int dz = 0; dz < 3; ++dz)
#pragma unroll
        for (int dy = 0; dy < 3; ++dy)
#pragma unroll
        for (int dx = 0; dx < 3; ++dx) {
            float v = tc[(lz+dz)*42 + (ly+dy)*7 + (lx+dx)];
            const float* wt = wc + ((dz*3 + dy)*3 + dx) * 12;  // uniform -> s_load_dwordx4
#pragma unroll
            for (int i = 0; i < 12; ++i)
                acc[i] = fmaf(wt[i], v, acc[i]);
        }
    }
    int gz = tz*4 + lz, gy = ty*4 + ly, gx = tx*4 + lx;
    size_t pp = (size_t)(gz*24 + gy)*24 + gx;
#pragma unroll
    for (int i = 0; i < 12; ++i)
        h2[((size_t)(b*48) + og*12 + i) * P + pp] = acc[i];
}

// ---------------- K3: 1x1x1 conv 48->48 (scalar weights) ----------------
__global__ __launch_bounds__(256) void k_conv3(const float* __restrict__ h2,
    const float* __restrict__ W3, const float* __restrict__ b3, float* __restrict__ h3)
{
    int t = blockIdx.x * 256 + threadIdx.x;
    int b = t / P, p = t % P;
    float acc[48];
#pragma unroll
    for (int o = 0; o < 48; ++o) acc[o] = b3[o];
    const float* hb = h2 + (size_t)b * 48 * P + p;
    for (int c = 0; c < 48; ++c) {
        float v = hb[(size_t)c * P];
#pragma unroll
        for (int o = 0; o < 48; ++o) acc[o] = fmaf(W3[o*48+c], v, acc[o]);   // uniform -> s_load
    }
    float* out = h3 + (size_t)b * 48 * P + p;
#pragma unroll
    for (int o = 0; o < 48; ++o) out[(size_t)o * P] = acc[o];
}

// ---------------- K4: instance-norm stats ----------------
__global__ __launch_bounds__(256) void k_in_stats(const float* __restrict__ h3,
                                                  float* __restrict__ stats)
{
    int bc = blockIdx.x;   // 0..95
    const float* src = h3 + (size_t)bc * P;
    float s = 0.f, s2 = 0.f;
    for (int i = threadIdx.x; i < P; i += 256) { float v = src[i]; s += v; s2 += v*v; }
    __shared__ float rs[4], rs2[4];
    for (int off = 32; off; off >>= 1) { s += __shfl_down(s, off); s2 += __shfl_down(s2, off); }
    int wid = threadIdx.x >> 6;
    if ((threadIdx.x & 63) == 0) { rs[wid] = s; rs2[wid] = s2; }
    __syncthreads();
    if (threadIdx.x == 0) {
        s = rs[0] + rs[1] + rs[2] + rs[3];
        s2 = rs2[0] + rs2[1] + rs2[2] + rs2[3];
        float m = s / (float)P;
        float var = s2 / (float)P - m * m;
        stats[bc*2] = m;
        stats[bc*2 + 1] = rsqrtf(var + 1e-5f);
    }
}

// ---------------- K5: normalize + SELU (in place) ----------------
__global__ __launch_bounds__(256) void k_in_apply(float* __restrict__ h3,
                                                  const float* __restrict__ stats)
{
    int t = blockIdx.x * 256 + threadIdx.x;  // NB*48*P exact
    int bc = t / P;
    float m = stats[bc*2], istd = stats[bc*2 + 1];
    float v = (h3[t] - m) * istd;
    const float kScale = 1.0507009873554805f, kAlpha = 1.6732632423543772f;
    h3[t] = v > 0.f ? kScale * v : kScale * kAlpha * expm1f(v);
}

// ---------------- K6: in_proj (u @ W^T -> xi, z) ----------------
__global__ __launch_bounds__(192) void k_inproj(const float* __restrict__ Lx,
    const float* __restrict__ Wip, float* __restrict__ xi, float* __restrict__ z)
{
    __shared__ float u[48 * 64];
    int b = blockIdx.x / 216; int l0 = (blockIdx.x % 216) * 64;
    for (int i = threadIdx.x; i < 48 * 64; i += 192) {
        int c = i >> 6, ll = i & 63;
        u[i] = Lx[((size_t)(b*48) + c) * P + l0 + ll];
    }
    __syncthreads();
    int e = threadIdx.x;   // 0..191
    float w[48];
#pragma unroll
    for (int c = 0; c < 48; ++c) w[c] = Wip[e*48 + c];
    float* dst = (e < 96) ? (xi + ((size_t)b * L + l0) * 96 + e)
                          : (z  + ((size_t)b * L + l0) * 96 + (e - 96));
    for (int ll = 0; ll < 64; ++ll) {
        float acc = 0.f;
#pragma unroll
        for (int c = 0; c < 48; ++c) acc = fmaf(w[c], u[c*64 + ll], acc);
        dst[(size_t)ll * 96] = acc;
    }
}

// ---------------- K7: depthwise causal conv1d + silu ----------------
__global__ __launch_bounds__(256) void k_conv1d(const float* __restrict__ xi,
    const float* __restrict__ cw, const float* __restrict__ cb, float* __restrict__ xs)
{
    int t = blockIdx.x * 256 + threadIdx.x;   // NB*L*96 exact
    int d = t % 96; int bl = t / 96; int l = bl % L; int b = bl / L;
    float acc = cb[d];
    const float* src = xi + ((size_t)b * L) * 96 + d;
#pragma unroll
    for (int k = 0; k < 4; ++k) {
        int ls = l - 3 + k;
        if (ls >= 0) acc = fmaf(cw[d*4 + k], src[(size_t)ls * 96], acc);
    }
    xs[t] = siluf(acc);
}

// ---------------- K8: x_proj + dt_proj + softplus (scalar weights) ----------------
__global__ __launch_bounds__(256) void k_xproj(const float* __restrict__ xs,
    const float* __restrict__ Wxp, const float* __restrict__ Wdt,
    const float* __restrict__ bdt, float* __restrict__ delta,
    float* __restrict__ Bm, float* __restrict__ Cm)
{
    int t = blockIdx.x * 256 + threadIdx.x;   // NB*L exact
    const float* row = xs + (size_t)t * 96;
    float xr[96];
#pragma unroll
    for (int i = 0; i < 24; ++i) {
        float4 v = ((const float4*)row)[i];
        xr[i*4] = v.x; xr[i*4+1] = v.y; xr[i*4+2] = v.z; xr[i*4+3] = v.w;
    }
    float dt0 = 0.f, dt1 = 0.f, dt2 = 0.f;
#pragma unroll
    for (int d = 0; d < 96; ++d) {
        dt0 = fmaf(Wxp[0*96 + d], xr[d], dt0);
        dt1 = fmaf(Wxp[1*96 + d], xr[d], dt1);
        dt2 = fmaf(Wxp[2*96 + d], xr[d], dt2);
    }
#pragma unroll
    for (int e = 0; e < 16; ++e) {
        float a = 0.f, c = 0.f;
#pragma unroll
        for (int d = 0; d < 96; ++d) {
            a = fmaf(Wxp[(3 + e)*96 + d], xr[d], a);
            c = fmaf(Wxp[(19 + e)*96 + d], xr[d], c);
        }
        Bm[(size_t)t * 16 + e] = a;
        Cm[(size_t)t * 16 + e] = c;
    }
    float* dl = delta + (size_t)t * 96;
#pragma unroll
    for (int d = 0; d < 96; ++d) {
        float v = fmaf(Wdt[d*3], dt0, fmaf(Wdt[d*3+1], dt1, fmaf(Wdt[d*3+2], dt2, bdt[d])));
        dl[d] = softplusf(v);
    }
}

// ---------------- K9: scan phase 1 (per-chunk local scan + dA product) ----------------
__global__ __launch_bounds__(256) void k_scan1(const float* __restrict__ delta,
    const float* __restrict__ xs, const float* __restrict__ Bm,
    const float* __restrict__ Alog, float* __restrict__ Aprod, float* __restrict__ hend)
{
    int wid = (blockIdx.x * 256 + threadIdx.x) >> 6;  // 0 .. NB*NCK*24-1
    int lane = threadIdx.x & 63;
    int dg = wid % 24; int ch = (wid / 24) % NCK; int b = wid / (24 * NCK);
    int dl = lane >> 4, n = lane & 15;
    int d = dg * 4 + dl;
    float A = -__expf(Alog[d*16 + n]);
    float h = 0.f, ap = 1.f;
    int t0 = ch * CHUNK;
    const float* dp = delta + ((size_t)b * L + t0) * 96 + d;
    const float* xp = xs    + ((size_t)b * L + t0) * 96 + d;
    const float* bp = Bm    + ((size_t)b * L + t0) * 16 + n;
    for (int t = 0; t < CHUNK; ++t) {
        float del = dp[(size_t)t * 96];
        float xv  = xp[(size_t)t * 96];
        float bv  = bp[(size_t)t * 16];
        float dA = __expf(del * A);
        h = fmaf(dA, h, del * xv * bv);
        ap *= dA;
    }
    size_t idx = (((size_t)b * NCK + ch) * 96 + d) * 16 + n;
    Aprod[idx] = ap;
    hend[idx]  = h;
}

// ---------------- K10: scan phase 2 (cross-chunk combine) ----------------
__global__ __launch_bounds__(256) void k_scan2(const float* __restrict__ Aprod,
    const float* __restrict__ hend, float* __restrict__ hin)
{
    int t = blockIdx.x * 256 + threadIdx.x;   // NB*1536 exact
    int b = t / 1536; int dn = t % 1536;
    float carry = 0.f;
    for (int j = 0; j < NCK; ++j) {
        size_t idx = ((size_t)b * NCK + j) * 1536 + dn;
        hin[idx] = carry;
        carry = fmaf(Aprod[idx], carry, hend[idx]);
    }
}

// ---------------- K11: scan phase 3 (replay + y = (scan + D*xs)*silu(z), in place over xs) ----------------
__global__ __launch_bounds__(256) void k_scan3(const float* __restrict__ delta,
    float* __restrict__ xs, const float* __restrict__ Bm, const float* __restrict__ Cm,
    const float* __restrict__ z, const float* __restrict__ Alog,
    const float* __restrict__ Dp, const float* __restrict__ hin)
{
    int wid = (blockIdx.x * 256 + threadIdx.x) >> 6;
    int lane = threadIdx.x & 63;
    int dg = wid % 24; int ch = (wid / 24) % NCK; int b = wid / (24 * NCK);
    int dl = lane >> 4, n = lane & 15;
    int d = dg * 4 + dl;
    float A = -__expf(Alog[d*16 + n]);
    float Dv = Dp[d];
    size_t cidx = (((size_t)b * NCK + ch) * 96 + d) * 16 + n;
    float h = hin[cidx];
    int t0 = ch * CHUNK;
    const float* dp = delta + ((size_t)b * L + t0) * 96 + d;
    float* xp       = xs    + ((size_t)b * L + t0) * 96 + d;
    const float* bp = Bm    + ((size_t)b * L + t0) * 16 + n;
    const float* cp = Cm    + ((size_t)b * L + t0) * 16 + n;
    const float* zp = z     + ((size_t)b * L + t0) * 96 + d;
    for (int t = 0; t < CHUNK; ++t) {
        float del = dp[(size_t)t * 96];
        float xv  = xp[(size_t)t * 96];
        float dA = __expf(del * A);
        h = fmaf(dA, h, del * xv * bp[(size_t)t * 16]);
        float yc = h * cp[(size_t)t * 16];
        yc += __shfl_xor(yc, 8);
        yc += __shfl_xor(yc, 4);
        yc += __shfl_xor(yc, 2);
        yc += __shfl_xor(yc, 1);
        if (n == 0) {
            float zv = zp[(size_t)t * 96];
            xp[(size_t)t * 96] = fmaf(Dv, xv, yc) * siluf(zv);
        }
    }
}

// ---------------- K12: out_proj + residual (scalar weights) ----------------
__global__ __launch_bounds__(256) void k_outproj(const float* __restrict__ y,
    const float* __restrict__ Wop, const float* __restrict__ Lx, float* __restrict__ out)
{
    int t = blockIdx.x * 256 + threadIdx.x;  // NB*P exact
    int b = t / P, p = t % P;
    const float* yr = y + (size_t)t * 96;
    float acc[48];
#pragma unroll
    for (int o = 0; o < 48; ++o) acc[o] = 0.f;
#pragma unroll
    for (int i = 0; i < 24; ++i) {
        float4 v4 = ((const float4*)yr)[i];
#pragma unroll
        for (int o = 0; o < 48; ++o) {
            acc[o] = fmaf(Wop[o*96 + i*4],     v4.x, acc[o]);
            acc[o] = fmaf(Wop[o*96 + i*4 + 1], v4.y, acc[o]);
            acc[o] = fmaf(Wop[o*96 + i*4 + 2], v4.z, acc[o]);
            acc[o] = fmaf(Wop[o*96 + i*4 + 3], v4.w, acc[o]);
        }
    }
    const float* lx = Lx + (size_t)b * 48 * P + p;
    float* op = out + (size_t)b * 48 * P + p;
#pragma unroll
    for (int o = 0; o < 48; ++o) op[(size_t)o * P] = acc[o] + lx[(size_t)o * P];
}

extern "C" void kernel_launch(void* const* d_in, const int* in_sizes, int n_in,
                              void* d_out, int out_size, void* d_ws, size_t ws_size,
                              hipStream_t stream) {
    const float* x        = (const float*)d_in[0];
    const float* Hx       = (const float*)d_in[1];
    const float* W1       = (const float*)d_in[2];
    const float* b1       = (const float*)d_in[3];
    const float* W2       = (const float*)d_in[4];
    const float* b2       = (const float*)d_in[5];
    const float* W3       = (const float*)d_in[6];
    const float* b3       = (const float*)d_in[7];
    const float* in_proj  = (const float*)d_in[8];
    const float* conv1d_w = (const float*)d_in[9];
    const float* conv1d_b = (const float*)d_in[10];
    const float* x_proj   = (const float*)d_in[11];
    const float* dt_proj  = (const float*)d_in[12];
    const float* dt_bias  = (const float*)d_in[13];
    const float* A_log    = (const float*)d_in[14];
    const float* D_param  = (const float*)d_in[15];
    const float* out_proj = (const float*)d_in[16];
    float* out = (float*)d_out;

    float* ws = (float*)d_ws;
    const size_t SZ_BCP = (size_t)NB * 48 * P;      // 1,327,104
    const size_t SZ_BLD = (size_t)NB * L * 96;      // 2,654,208
    const size_t SZ_BLN = (size_t)NB * L * 16;      //   442,368
    const size_t SZ_CK  = (size_t)NB * NCK * 1536;  //   331,776
    float* bufA  = ws;                    // h1; later delta (spans bufA+bufB)
    float* bufB  = bufA + SZ_BCP;         // h2
    float* bufC  = bufB + SZ_BCP;         // h3 -> Lx (in place)
    float* xib   = bufC + SZ_BCP;         // xi
    float* zb    = xib  + SZ_BLD;         // z
    float* xsb   = zb   + SZ_BLD;         // xs, then y (in place)
    float* Bmb   = xsb  + SZ_BLD;
    float* Cmb   = Bmb  + SZ_BLN;
    float* Apr   = Cmb  + SZ_BLN;
    float* hendb = Apr  + SZ_CK;
    float* hinb  = hendb+ SZ_CK;
    float* stats = hinb + SZ_CK;          // 192 floats
    float* Wtb   = stats + 192;           // 62,208 floats (transposed W2)
    float* deltab = bufA;                 // reuses h1+h2 (free after k_conv3)

    k_wtrans<<<243, 256, 0, stream>>>(W2, Wtb);
    k_conv1<<<108, 256, 0, stream>>>(x, Hx, W1, b1, bufA);
    k_conv2<<<NB * 216, 256, 0, stream>>>(bufA, Wtb, b2, bufB);
    k_conv3<<<108, 256, 0, stream>>>(bufB, W3, b3, bufC);
    k_in_stats<<<NB * 48, 256, 0, stream>>>(bufC, stats);
    k_in_apply<<<5184, 256, 0, stream>>>(bufC, stats);
    k_inproj<<<NB * 216, 192, 0, stream>>>(bufC, in_proj, xib, zb);
    k_conv1d<<<10368, 256, 0, stream>>>(xib, conv1d_w, conv1d_b, xsb);
    k_xproj<<<108, 256, 0, stream>>>(xsb, x_proj, dt_proj, dt_bias, deltab, Bmb, Cmb);
    k_scan1<<<(NB * NCK * 24) / 4, 256, 0, stream>>>(deltab, xsb, Bmb, A_log, Apr, hendb);
    k_scan2<<<12, 256, 0, stream>>>(Apr, hendb, hinb);
    k_scan3<<<(NB * NCK * 24) / 4, 256, 0, stream>>>(deltab, xsb, Bmb, Cmb, zb, A_log,
                                                     D_param, hinb);
    k_outproj<<<108, 256, 0, stream>>>(xsb, out_proj, bufC, out);
}

// Round 3
// 433.125 us; speedup vs baseline: 1.5157x; 1.1439x over previous
//
#include <hip/hip_runtime.h>
#include <math.h>

#define NB 2
#define NCH 48
#define P 13824        // 24^3
#define DI 96
#define NSTATE 16
#define L 13824
#define CHUNK 128
#define NCK 108        // L / CHUNK

__device__ __forceinline__ float siluf(float x) { return x / (1.f + __expf(-x)); }
__device__ __forceinline__ float softplusf(float x) {
    return x > 0.f ? x + log1pf(expf(-x)) : log1pf(expf(x));
}

// ---------------- K0: transpose W2 [48o][48c][27t] -> Wt [4og][48c][27t][12i] ----------------
__global__ __launch_bounds__(256) void k_wtrans(const float* __restrict__ W2,
                                                float* __restrict__ Wt)
{
    int i = blockIdx.x * 256 + threadIdx.x;      // 62208 = 243*256 exact
    int o = i / (48 * 27); int r = i % (48 * 27); int c = r / 27; int tap = r % 27;
    int og = o / 12, oi = o % 12;
    Wt[(((og * 48 + c) * 27 + tap) * 12) + oi] = W2[i];
}

// ---------------- K1: upsample(2x trilinear) + concat + 1x1x1 conv (scalar weights) ----------------
__global__ __launch_bounds__(256) void k_conv1(const float* __restrict__ x,
    const float* __restrict__ Hx, const float* __restrict__ W1,
    const float* __restrict__ b1, float* __restrict__ h1)
{
    int t = blockIdx.x * 256 + threadIdx.x;   // 0 .. NB*P-1
    int b = t / P, p = t % P;
    int zi = p / 576, yi = (p / 24) % 24, xi_ = p % 24;
    float fpos; int z0, z1, y0, y1, x0, x1; float wz, wy, wx;
    fpos = (float)(zi * 11) / 23.0f; z0 = (int)floorf(fpos); wz = fpos - z0; z1 = min(z0 + 1, 11);
    fpos = (float)(yi * 11) / 23.0f; y0 = (int)floorf(fpos); wy = fpos - y0; y1 = min(y0 + 1, 11);
    fpos = (float)(xi_ * 11) / 23.0f; x0 = (int)floorf(fpos); wx = fpos - x0; x1 = min(x0 + 1, 11);
    float acc[48];
#pragma unroll
    for (int o = 0; o < 48; ++o) acc[o] = b1[o];          // uniform -> s_load
    const float* xb = x + (size_t)b * 48 * 1728;
    for (int c = 0; c < 48; ++c) {
        const float* xc = xb + c * 1728;
        float v00 = xc[(z0*12+y0)*12+x0]*(1.f-wx) + xc[(z0*12+y0)*12+x1]*wx;
        float v01 = xc[(z0*12+y1)*12+x0]*(1.f-wx) + xc[(z0*12+y1)*12+x1]*wx;
        float v10 = xc[(z1*12+y0)*12+x0]*(1.f-wx) + xc[(z1*12+y0)*12+x1]*wx;
        float v11 = xc[(z1*12+y1)*12+x0]*(1.f-wx) + xc[(z1*12+y1)*12+x1]*wx;
        float v = (v00*(1.f-wy)+v01*wy)*(1.f-wz) + (v10*(1.f-wy)+v11*wy)*wz;
#pragma unroll
        for (int o = 0; o < 48; ++o) acc[o] = fmaf(W1[o*144+c], v, acc[o]);   // uniform -> s_load
    }
    const float* hb = Hx + (size_t)b * 96 * P + p;
    for (int c = 0; c < 96; ++c) {
        float v = hb[(size_t)c * P];
#pragma unroll
        for (int o = 0; o < 48; ++o) acc[o] = fmaf(W1[o*144+48+c], v, acc[o]); // uniform -> s_load
    }
    float* out = h1 + (size_t)b * 48 * P + p;
#pragma unroll
    for (int o = 0; o < 48; ++o) out[(size_t)o * P] = acc[o];
}

// ---------------- K2: 3x3x3 conv, pad 1, 48->48, LDS tile + SGPR weights ----------------
__global__ __launch_bounds__(256) void k_conv2(const float* __restrict__ h1,
    const float* __restrict__ Wt, const float* __restrict__ b2, float* __restrict__ h2)
{
    __shared__ float tile[48 * 252];   // 48 x 6z x 6y x 7x (x padded 6->7)
    int blk = blockIdx.x;              // b*216 + tz*36 + ty*6 + tx
    int b = blk / 216; int r = blk % 216;
    int tz = r / 36, ty = (r / 6) % 6, tx = r % 6;
    int z0 = tz*4 - 1, y0 = ty*4 - 1, x0 = tx*4 - 1;
    for (int i = threadIdx.x; i < 48 * 216; i += 256) {
        int c = i / 216; int q = i % 216;
        int lz = q / 36, ly = (q / 6) % 6, lx = q % 6;
        int gz = z0 + lz, gy = y0 + ly, gx = x0 + lx;
        float v = 0.f;
        if ((unsigned)gz < 24u && (unsigned)gy < 24u && (unsigned)gx < 24u)
            v = h1[((size_t)(b*48 + c)) * P + (gz*24 + gy)*24 + gx];
        tile[c*252 + (lz*6 + ly)*7 + lx] = v;
    }
    __syncthreads();
    int lp = threadIdx.x & 63;
    int og = __builtin_amdgcn_readfirstlane((int)(threadIdx.x >> 6));  // SGPR -> scalar weight path
    int lz = lp >> 4, ly = (lp >> 2) & 3, lx = lp & 3;
    float acc[12];
#pragma unroll
    for (int i = 0; i < 12; ++i) acc[i] = b2[og*12 + i];   // uniform -> s_load
    const float* wb = Wt + (size_t)og * 48 * 27 * 12;
    for (int c = 0; c < 48; ++c) {
        const float* tc = tile + c * 252;
        const float* wc = wb + c * 27 * 12;
#pragma unroll
        for (int dz = 0; dz < 3; ++dz)
#pragma unroll
        for (int dy = 0; dy < 3; ++dy)
#pragma unroll
        for (int dx = 0; dx < 3; ++dx) {
            float v = tc[(lz+dz)*42 + (ly+dy)*7 + (lx+dx)];
            const float* wt = wc + ((dz*3 + dy)*3 + dx) * 12;  // uniform -> s_load_dwordx4
#pragma unroll
            for (int i = 0; i < 12; ++i)
                acc[i] = fmaf(wt[i], v, acc[i]);
        }
    }
    int gz = tz*4 + lz, gy = ty*4 + ly, gx = tx*4 + lx;
    size_t pp = (size_t)(gz*24 + gy)*24 + gx;
#pragma unroll
    for (int i = 0; i < 12; ++i)
        h2[((size_t)(b*48) + og*12 + i) * P + pp] = acc[i];
}

// ---------------- K3: 1x1x1 conv 48->48 (scalar weights) ----------------
__global__ __launch_bounds__(256) void k_conv3(const float* __restrict__ h2,
    const float* __restrict__ W3, const float* __restrict__ b3, float* __restrict__ h3)
{
    int t = blockIdx.x * 256 + threadIdx.x;
    int b = t / P, p = t % P;
    float acc[48];
#pragma unroll
    for (int o = 0; o < 48; ++o) acc[o] = b3[o];
    const float* hb = h2 + (size_t)b * 48 * P + p;
    for (int c = 0; c < 48; ++c) {
        float v = hb[(size_t)c * P];
#pragma unroll
        for (int o = 0; o < 48; ++o) acc[o] = fmaf(W3[o*48+c], v, acc[o]);   // uniform -> s_load
    }
    float* out = h3 + (size_t)b * 48 * P + p;
#pragma unroll
    for (int o = 0; o < 48; ++o) out[(size_t)o * P] = acc[o];
}

// ---------------- K4: instance-norm stats ----------------
__global__ __launch_bounds__(256) void k_in_stats(const float* __restrict__ h3,
                                                  float* __restrict__ stats)
{
    int bc = blockIdx.x;   // 0..95
    const float* src = h3 + (size_t)bc * P;
    float s = 0.f, s2 = 0.f;
    for (int i = threadIdx.x; i < P; i += 256) { float v = src[i]; s += v; s2 += v*v; }
    __shared__ float rs[4], rs2[4];
    for (int off = 32; off; off >>= 1) { s += __shfl_down(s, off); s2 += __shfl_down(s2, off); }
    int wid = threadIdx.x >> 6;
    if ((threadIdx.x & 63) == 0) { rs[wid] = s; rs2[wid] = s2; }
    __syncthreads();
    if (threadIdx.x == 0) {
        s = rs[0] + rs[1] + rs[2] + rs[3];
        s2 = rs2[0] + rs2[1] + rs2[2] + rs2[3];
        float m = s / (float)P;
        float var = s2 / (float)P - m * m;
        stats[bc*2] = m;
        stats[bc*2 + 1] = rsqrtf(var + 1e-5f);
    }
}

// ---------------- K5: normalize + SELU (in place) ----------------
__global__ __launch_bounds__(256) void k_in_apply(float* __restrict__ h3,
                                                  const float* __restrict__ stats)
{
    int t = blockIdx.x * 256 + threadIdx.x;  // NB*48*P exact
    int bc = t / P;
    float m = stats[bc*2], istd = stats[bc*2 + 1];
    float v = (h3[t] - m) * istd;
    const float kScale = 1.0507009873554805f, kAlpha = 1.6732632423543772f;
    h3[t] = v > 0.f ? kScale * v : kScale * kAlpha * expm1f(v);
}

// ---------------- K6: in_proj (u @ W^T -> xi, z) ----------------
__global__ __launch_bounds__(192) void k_inproj(const float* __restrict__ Lx,
    const float* __restrict__ Wip, float* __restrict__ xi, float* __restrict__ z)
{
    __shared__ float u[48 * 64];
    int b = blockIdx.x / 216; int l0 = (blockIdx.x % 216) * 64;
    for (int i = threadIdx.x; i < 48 * 64; i += 192) {
        int c = i >> 6, ll = i & 63;
        u[i] = Lx[((size_t)(b*48) + c) * P + l0 + ll];
    }
    __syncthreads();
    int e = threadIdx.x;   // 0..191
    float w[48];
#pragma unroll
    for (int c = 0; c < 48; ++c) w[c] = Wip[e*48 + c];
    float* dst = (e < 96) ? (xi + ((size_t)b * L + l0) * 96 + e)
                          : (z  + ((size_t)b * L + l0) * 96 + (e - 96));
    for (int ll = 0; ll < 64; ++ll) {
        float acc = 0.f;
#pragma unroll
        for (int c = 0; c < 48; ++c) acc = fmaf(w[c], u[c*64 + ll], acc);
        dst[(size_t)ll * 96] = acc;
    }
}

// ---------------- K7: depthwise causal conv1d + silu ----------------
__global__ __launch_bounds__(256) void k_conv1d(const float* __restrict__ xi,
    const float* __restrict__ cw, const float* __restrict__ cb, float* __restrict__ xs)
{
    int t = blockIdx.x * 256 + threadIdx.x;   // NB*L*96 exact
    int d = t % 96; int bl = t / 96; int l = bl % L; int b = bl / L;
    float acc = cb[d];
    const float* src = xi + ((size_t)b * L) * 96 + d;
#pragma unroll
    for (int k = 0; k < 4; ++k) {
        int ls = l - 3 + k;
        if (ls >= 0) acc = fmaf(cw[d*4 + k], src[(size_t)ls * 96], acc);
    }
    xs[t] = siluf(acc);
}

// ---------------- K8: x_proj + dt_proj + softplus (scalar weights) ----------------
__global__ __launch_bounds__(256) void k_xproj(const float* __restrict__ xs,
    const float* __restrict__ Wxp, const float* __restrict__ Wdt,
    const float* __restrict__ bdt, float* __restrict__ delta,
    float* __restrict__ Bm, float* __restrict__ Cm)
{
    int t = blockIdx.x * 256 + threadIdx.x;   // NB*L exact
    const float* row = xs + (size_t)t * 96;
    float xr[96];
#pragma unroll
    for (int i = 0; i < 24; ++i) {
        float4 v = ((const float4*)row)[i];
        xr[i*4] = v.x; xr[i*4+1] = v.y; xr[i*4+2] = v.z; xr[i*4+3] = v.w;
    }
    float dt0 = 0.f, dt1 = 0.f, dt2 = 0.f;
#pragma unroll
    for (int d = 0; d < 96; ++d) {
        dt0 = fmaf(Wxp[0*96 + d], xr[d], dt0);
        dt1 = fmaf(Wxp[1*96 + d], xr[d], dt1);
        dt2 = fmaf(Wxp[2*96 + d], xr[d], dt2);
    }
#pragma unroll
    for (int e = 0; e < 16; ++e) {
        float a = 0.f, c = 0.f;
#pragma unroll
        for (int d = 0; d < 96; ++d) {
            a = fmaf(Wxp[(3 + e)*96 + d], xr[d], a);
            c = fmaf(Wxp[(19 + e)*96 + d], xr[d], c);
        }
        Bm[(size_t)t * 16 + e] = a;
        Cm[(size_t)t * 16 + e] = c;
    }
    float* dl = delta + (size_t)t * 96;
#pragma unroll
    for (int d = 0; d < 96; ++d) {
        float v = fmaf(Wdt[d*3], dt0, fmaf(Wdt[d*3+1], dt1, fmaf(Wdt[d*3+2], dt2, bdt[d])));
        dl[d] = softplusf(v);
    }
}

// ---------------- K9: scan phase 1 — software-pipelined (unroll 8, dual 4-blocks) ----------------
__global__ __launch_bounds__(256) void k_scan1(const float* __restrict__ delta,
    const float* __restrict__ xs, const float* __restrict__ Bm,
    const float* __restrict__ Alog, float* __restrict__ Aprod, float* __restrict__ hend)
{
    int wid = (blockIdx.x * 256 + threadIdx.x) >> 6;  // 0 .. NB*NCK*24-1
    int lane = threadIdx.x & 63;
    int dg = wid % 24; int ch = (wid / 24) % NCK; int b = wid / (24 * NCK);
    int dl = lane >> 4, n = lane & 15;
    int d = dg * 4 + dl;
    float A = -__expf(Alog[d*16 + n]);
    float h = 0.f, ap = 1.f;
    int t0 = ch * CHUNK;
    const float* dp = delta + ((size_t)b * L + t0) * 96 + d;
    const float* xp = xs    + ((size_t)b * L + t0) * 96 + d;
    const float* bp = Bm    + ((size_t)b * L + t0) * 16 + n;

    float dA0, dA1, dA2, dA3, xA0, xA1, xA2, xA3, bA0, bA1, bA2, bA3;
    float dB0, dB1, dB2, dB3, xB0, xB1, xB2, xB3, bB0, bB1, bB2, bB3;
#define LD1(s, T) do { \
    d##s##0 = dp[(size_t)(T)*96];     x##s##0 = xp[(size_t)(T)*96];     b##s##0 = bp[(size_t)(T)*16]; \
    d##s##1 = dp[(size_t)((T)+1)*96]; x##s##1 = xp[(size_t)((T)+1)*96]; b##s##1 = bp[(size_t)((T)+1)*16]; \
    d##s##2 = dp[(size_t)((T)+2)*96]; x##s##2 = xp[(size_t)((T)+2)*96]; b##s##2 = bp[(size_t)((T)+2)*16]; \
    d##s##3 = dp[(size_t)((T)+3)*96]; x##s##3 = xp[(size_t)((T)+3)*96]; b##s##3 = bp[(size_t)((T)+3)*16]; \
  } while (0)
#define CMP1(s) do { \
    float e0 = __expf(d##s##0 * A); float e1 = __expf(d##s##1 * A); \
    float e2 = __expf(d##s##2 * A); float e3 = __expf(d##s##3 * A); \
    h = fmaf(e0, h, d##s##0 * x##s##0 * b##s##0); \
    h = fmaf(e1, h, d##s##1 * x##s##1 * b##s##1); \
    h = fmaf(e2, h, d##s##2 * x##s##2 * b##s##2); \
    h = fmaf(e3, h, d##s##3 * x##s##3 * b##s##3); \
    ap *= e0 * e1 * e2 * e3; \
  } while (0)

    LD1(A, 0);
#pragma unroll 1
    for (int t = 0; t < CHUNK; t += 8) {
        LD1(B, t + 4);
        CMP1(A);
        if (t + 8 < CHUNK) LD1(A, t + 8);
        CMP1(B);
    }
#undef LD1
#undef CMP1
    size_t idx = (((size_t)b * NCK + ch) * 96 + d) * 16 + n;
    Aprod[idx] = ap;
    hend[idx]  = h;
}

// ---------------- K10: scan phase 2 (cross-chunk combine, prefetch 4 ahead) ----------------
__global__ __launch_bounds__(256) void k_scan2(const float* __restrict__ Aprod,
    const float* __restrict__ hend, float* __restrict__ hin)
{
    int t = blockIdx.x * 256 + threadIdx.x;   // NB*1536 exact
    int b = t / 1536; int dn = t % 1536;
    const float* ap = Aprod + (size_t)b * NCK * 1536 + dn;
    const float* he = hend  + (size_t)b * NCK * 1536 + dn;
    float* hi       = hin   + (size_t)b * NCK * 1536 + dn;
    float carry = 0.f;
    float aA0, aA1, aA2, aA3, hA0, hA1, hA2, hA3;
    float aB0, aB1, aB2, aB3, hB0, hB1, hB2, hB3;
#define LD2(s, J) do { \
    a##s##0 = ap[(size_t)(J)*1536];     h##s##0 = he[(size_t)(J)*1536]; \
    a##s##1 = ap[(size_t)((J)+1)*1536]; h##s##1 = he[(size_t)((J)+1)*1536]; \
    a##s##2 = ap[(size_t)((J)+2)*1536]; h##s##2 = he[(size_t)((J)+2)*1536]; \
    a##s##3 = ap[(size_t)((J)+3)*1536]; h##s##3 = he[(size_t)((J)+3)*1536]; \
  } while (0)
#define CMP2(s, J) do { \
    hi[(size_t)(J)*1536]     = carry; carry = fmaf(a##s##0, carry, h##s##0); \
    hi[(size_t)((J)+1)*1536] = carry; carry = fmaf(a##s##1, carry, h##s##1); \
    hi[(size_t)((J)+2)*1536] = carry; carry = fmaf(a##s##2, carry, h##s##2); \
    hi[(size_t)((J)+3)*1536] = carry; carry = fmaf(a##s##3, carry, h##s##3); \
  } while (0)
    LD2(A, 0);
#pragma unroll 1
    for (int j = 0; j < 104; j += 8) {        // 104 = 13*8; tail 4 handled after
        LD2(B, j + 4);
        CMP2(A, j);
        if (j + 8 < NCK) LD2(A, j + 8);
        CMP2(B, j + 4);
    }
    LD2(A, 104);
    CMP2(A, 104);
#undef LD2
#undef CMP2
}

// ---------------- K11: scan phase 3 — software-pipelined replay + y, in place over xs ----------------
__global__ __launch_bounds__(256) void k_scan3(const float* __restrict__ delta,
    float* __restrict__ xs, const float* __restrict__ Bm, const float* __restrict__ Cm,
    const float* __restrict__ z, const float* __restrict__ Alog,
    const float* __restrict__ Dp, const float* __restrict__ hin)
{
    int wid = (blockIdx.x * 256 + threadIdx.x) >> 6;
    int lane = threadIdx.x & 63;
    int dg = wid % 24; int ch = (wid / 24) % NCK; int b = wid / (24 * NCK);
    int dl = lane >> 4, n = lane & 15;
    int d = dg * 4 + dl;
    float A = -__expf(Alog[d*16 + n]);
    float Dv = Dp[d];
    size_t cidx = (((size_t)b * NCK + ch) * 96 + d) * 16 + n;
    float h = hin[cidx];
    int t0 = ch * CHUNK;
    const float* dp = delta + ((size_t)b * L + t0) * 96 + d;
    float* xp       = xs    + ((size_t)b * L + t0) * 96 + d;
    const float* bp = Bm    + ((size_t)b * L + t0) * 16 + n;
    const float* cp = Cm    + ((size_t)b * L + t0) * 16 + n;
    const float* zp = z     + ((size_t)b * L + t0) * 96 + d;

    float dA0, dA1, dA2, dA3, xA0, xA1, xA2, xA3, bA0, bA1, bA2, bA3, cA0, cA1, cA2, cA3, zA0, zA1, zA2, zA3;
    float dB0, dB1, dB2, dB3, xB0, xB1, xB2, xB3, bB0, bB1, bB2, bB3, cB0, cB1, cB2, cB3, zB0, zB1, zB2, zB3;
#define LD3(s, T) do { \
    d##s##0 = dp[(size_t)(T)*96];     x##s##0 = xp[(size_t)(T)*96];     b##s##0 = bp[(size_t)(T)*16]; \
    c##s##0 = cp[(size_t)(T)*16];     z##s##0 = zp[(size_t)(T)*96]; \
    d##s##1 = dp[(size_t)((T)+1)*96]; x##s##1 = xp[(size_t)((T)+1)*96]; b##s##1 = bp[(size_t)((T)+1)*16]; \
    c##s##1 = cp[(size_t)((T)+1)*16]; z##s##1 = zp[(size_t)((T)+1)*96]; \
    d##s##2 = dp[(size_t)((T)+2)*96]; x##s##2 = xp[(size_t)((T)+2)*96]; b##s##2 = bp[(size_t)((T)+2)*16]; \
    c##s##2 = cp[(size_t)((T)+2)*16]; z##s##2 = zp[(size_t)((T)+2)*96]; \
    d##s##3 = dp[(size_t)((T)+3)*96]; x##s##3 = xp[(size_t)((T)+3)*96]; b##s##3 = bp[(size_t)((T)+3)*16]; \
    c##s##3 = cp[(size_t)((T)+3)*16]; z##s##3 = zp[(size_t)((T)+3)*96]; \
  } while (0)
#define STEP3(DEL, XV, BV, CV, ZV, T) do { \
    float dAv = __expf((DEL) * A); \
    h = fmaf(dAv, h, (DEL) * (XV) * (BV)); \
    float yc = h * (CV); \
    yc += __shfl_xor(yc, 8); \
    yc += __shfl_xor(yc, 4); \
    yc += __shfl_xor(yc, 2); \
    yc += __shfl_xor(yc, 1); \
    if (n == 0) xp[(size_t)(T)*96] = fmaf(Dv, (XV), yc) * siluf(ZV); \
  } while (0)
#define CMP3(s, T) do { \
    STEP3(d##s##0, x##s##0, b##s##0, c##s##0, z##s##0, (T)); \
    STEP3(d##s##1, x##s##1, b##s##1, c##s##1, z##s##1, (T)+1); \
    STEP3(d##s##2, x##s##2, b##s##2, c##s##2, z##s##2, (T)+2); \
    STEP3(d##s##3, x##s##3, b##s##3, c##s##3, z##s##3, (T)+3); \
  } while (0)

    LD3(A, 0);
#pragma unroll 1
    for (int t = 0; t < CHUNK; t += 8) {
        LD3(B, t + 4);
        CMP3(A, t);
        if (t + 8 < CHUNK) LD3(A, t + 8);
        CMP3(B, t + 4);
    }
#undef LD3
#undef STEP3
#undef CMP3
}

// ---------------- K12: out_proj + residual (scalar weights) ----------------
__global__ __launch_bounds__(256) void k_outproj(const float* __restrict__ y,
    const float* __restrict__ Wop, const float* __restrict__ Lx, float* __restrict__ out)
{
    int t = blockIdx.x * 256 + threadIdx.x;  // NB*P exact
    int b = t / P, p = t % P;
    const float* yr = y + (size_t)t * 96;
    float acc[48];
#pragma unroll
    for (int o = 0; o < 48; ++o) acc[o] = 0.f;
#pragma unroll
    for (int i = 0; i < 24; ++i) {
        float4 v4 = ((const float4*)yr)[i];
#pragma unroll
        for (int o = 0; o < 48; ++o) {
            acc[o] = fmaf(Wop[o*96 + i*4],     v4.x, acc[o]);
            acc[o] = fmaf(Wop[o*96 + i*4 + 1], v4.y, acc[o]);
            acc[o] = fmaf(Wop[o*96 + i*4 + 2], v4.z, acc[o]);
            acc[o] = fmaf(Wop[o*96 + i*4 + 3], v4.w, acc[o]);
        }
    }
    const float* lx = Lx + (size_t)b * 48 * P + p;
    float* op = out + (size_t)b * 48 * P + p;
#pragma unroll
    for (int o = 0; o < 48; ++o) op[(size_t)o * P] = acc[o] + lx[(size_t)o * P];
}

extern "C" void kernel_launch(void* const* d_in, const int* in_sizes, int n_in,
                              void* d_out, int out_size, void* d_ws, size_t ws_size,
                              hipStream_t stream) {
    const float* x        = (const float*)d_in[0];
    const float* Hx       = (const float*)d_in[1];
    const float* W1       = (const float*)d_in[2];
    const float* b1       = (const float*)d_in[3];
    const float* W2       = (const float*)d_in[4];
    const float* b2       = (const float*)d_in[5];
    const float* W3       = (const float*)d_in[6];
    const float* b3       = (const float*)d_in[7];
    const float* in_proj  = (const float*)d_in[8];
    const float* conv1d_w = (const float*)d_in[9];
    const float* conv1d_b = (const float*)d_in[10];
    const float* x_proj   = (const float*)d_in[11];
    const float* dt_proj  = (const float*)d_in[12];
    const float* dt_bias  = (const float*)d_in[13];
    const float* A_log    = (const float*)d_in[14];
    const float* D_param  = (const float*)d_in[15];
    const float* out_proj = (const float*)d_in[16];
    float* out = (float*)d_out;

    float* ws = (float*)d_ws;
    const size_t SZ_BCP = (size_t)NB * 48 * P;      // 1,327,104
    const size_t SZ_BLD = (size_t)NB * L * 96;      // 2,654,208
    const size_t SZ_BLN = (size_t)NB * L * 16;      //   442,368
    const size_t SZ_CK  = (size_t)NB * NCK * 1536;  //   331,776
    float* bufA  = ws;                    // h1; later delta (spans bufA+bufB)
    float* bufB  = bufA + SZ_BCP;         // h2
    float* bufC  = bufB + SZ_BCP;         // h3 -> Lx (in place)
    float* xib   = bufC + SZ_BCP;         // xi
    float* zb    = xib  + SZ_BLD;         // z
    float* xsb   = zb   + SZ_BLD;         // xs, then y (in place)
    float* Bmb   = xsb  + SZ_BLD;
    float* Cmb   = Bmb  + SZ_BLN;
    float* Apr   = Cmb  + SZ_BLN;
    float* hendb = Apr  + SZ_CK;
    float* hinb  = hendb+ SZ_CK;
    float* stats = hinb + SZ_CK;          // 192 floats
    float* Wtb   = stats + 192;           // 62,208 floats (transposed W2)
    float* deltab = bufA;                 // reuses h1+h2 (free after k_conv3)

    k_wtrans<<<243, 256, 0, stream>>>(W2, Wtb);
    k_conv1<<<108, 256, 0, stream>>>(x, Hx, W1, b1, bufA);
    k_conv2<<<NB * 216, 256, 0, stream>>>(bufA, Wtb, b2, bufB);
    k_conv3<<<108, 256, 0, stream>>>(bufB, W3, b3, bufC);
    k_in_stats<<<NB * 48, 256, 0, stream>>>(bufC, stats);
    k_in_apply<<<5184, 256, 0, stream>>>(bufC, stats);
    k_inproj<<<NB * 216, 192, 0, stream>>>(bufC, in_proj, xib, zb);
    k_conv1d<<<10368, 256, 0, stream>>>(xib, conv1d_w, conv1d_b, xsb);
    k_xproj<<<108, 256, 0, stream>>>(xsb, x_proj, dt_proj, dt_bias, deltab, Bmb, Cmb);
    k_scan1<<<(NB * NCK * 24) / 4, 256, 0, stream>>>(deltab, xsb, Bmb, A_log, Apr, hendb);
    k_scan2<<<12, 256, 0, stream>>>(Apr, hendb, hinb);
    k_scan3<<<(NB * NCK * 24) / 4, 256, 0, stream>>>(deltab, xsb, Bmb, Cmb, zb, A_log,
                                                     D_param, hinb);
    k_outproj<<<108, 256, 0, stream>>>(xsb, out_proj, bufC, out);
}